// Round 16
// baseline (455.405 us; speedup 1.0000x reference)
//
#include <hip/hip_runtime.h>
#include <hip/hip_bf16.h>
#include <stdint.h>

#define NG 128
#define EPSI 1e-5f

typedef __attribute__((ext_vector_type(8))) __bf16 bf16x8;
typedef __attribute__((ext_vector_type(4))) float f32x4;
typedef unsigned int u32x4 __attribute__((ext_vector_type(4)));

union ABFrag { bf16x8 v; unsigned short u[8]; uint4 q; };
union U8 { uint4 q; unsigned short u[8]; u32x4 e; };

__device__ __forceinline__ float b2f(unsigned short u){
  union { unsigned int i; float f; } v; v.i = ((unsigned int)u) << 16; return v.f;
}
__device__ __forceinline__ unsigned short f2b(float f){
  union { float f; unsigned int i; } v; v.f = f;
  unsigned int r = v.i + 0x7fffu + ((v.i >> 16) & 1u);
  return (unsigned short)(r >> 16);
}
// pack 2 f32 -> 2 bf16 (RNE), lo in bits[15:0], hi in bits[31:16]
__device__ __forceinline__ unsigned int pk2(float lo, float hi){
  unsigned int r;
  asm("v_cvt_pk_bf16_f32 %0, %1, %2" : "=v"(r) : "v"(lo), "v"(hi));
  return r;
}

// ---------------- prep: W1/W2 bf16 conversions (frag order), node hist ----------------
__global__ void kprep(const float* __restrict__ W1, const float* __restrict__ W2,
                      const int* __restrict__ ei,
                      unsigned short* __restrict__ WcF, unsigned short* __restrict__ W2F,
                      unsigned int* __restrict__ nodeh, int E){
  int idx = blockIdx.x * 256 + threadIdx.x;
  int stride = gridDim.x * 256;
  for (int i = idx; i < 32 * 2 * 64 * 8; i += stride){
    int j = i & 7, lane = (i >> 3) & 63, ks = (i >> 9) & 1, tn = i >> 10;
    int quad = lane >> 4, l15 = lane & 15;
    int k = ks * 32 + quad * 8 + j;
    int n = tn * 16 + l15;
    float wv = (n < 256) ? W1[k * 256 + n] : W1[(k + 64) * 256 + (n - 256)];
    WcF[i] = f2b(wv);
  }
  for (int i = idx; i < 4 * 8 * 64 * 8; i += stride){
    int j = i & 7, lane = (i >> 3) & 63, ks = (i >> 9) & 7, w = i >> 12;
    int quad = lane >> 4, l15 = lane & 15;
    W2F[i] = f2b(W2[(ks * 32 + quad * 8 + j) * 64 + w * 16 + l15]);
  }
  for (int e = idx; e < E; e += stride)
    atomicAdd(&nodeh[ei[e]], 1u);
}

// --- graph hist from node hist: hist[g] = sum nodeh[n] for n in g (batch sorted) ---
__global__ void khist(const unsigned int* __restrict__ nodeh, const int* __restrict__ batch,
                      unsigned int* __restrict__ hist, int N){
  __shared__ unsigned int h[NG];
  for (int i = threadIdx.x; i < NG; i += 256) h[i] = 0;
  __syncthreads();
  int idx = blockIdx.x * 256 + threadIdx.x;
  for (int i = idx; i < N; i += gridDim.x * 256)
    atomicAdd(&h[batch[i]], nodeh[i]);
  __syncthreads();
  for (int i = threadIdx.x; i < NG; i += 256)
    if (h[i]) atomicAdd(&hist[i], h[i]);
}

// --- scan: one block per graph. Computes padded-base prefix (pbase) from hist,
//     binary-searches this graph's node range, exclusive-scans nodeh into ncursor,
//     fills ecn coalesced (node id per edge slot), pre-fills pads, writes tilegid. ---
__global__ void __launch_bounds__(256) kscan(const unsigned int* __restrict__ nodeh,
                      const unsigned int* __restrict__ hist,
                      const int* __restrict__ batch,
                      unsigned int* __restrict__ ncursor,
                      unsigned int* __restrict__ gmeta,
                      int* __restrict__ ecn, int* __restrict__ ern,
                      int* __restrict__ eorig, int* __restrict__ tilegid, int N){
  __shared__ unsigned int sh[3];     // pbase, lo, hi
  __shared__ unsigned int wtot[4];
  int g = blockIdx.x;
  int t = threadIdx.x;
  // padded-count prefix over graphs < g (redundant per block; trivial work)
  unsigned int part = 0;
  for (int i = t; i < g; i += 256) part += (hist[i] + 31u) & ~31u;
  #pragma unroll
  for (int d = 1; d < 64; d <<= 1) part += __shfl_xor(part, d);
  if ((t & 63) == 0) wtot[t >> 6] = part;
  // node range via binary search on sorted batch
  if (t == 64 || t == 65){
    int target = g + (t - 64);
    int lo = 0, hi = N;
    while (lo < hi){ int mid = (lo + hi) >> 1; if (batch[mid] < target) lo = mid + 1; else hi = mid; }
    sh[1 + (t - 64)] = lo;
  }
  __syncthreads();
  if (t == 0){
    unsigned int pb = wtot[0] + wtot[1] + wtot[2] + wtot[3];
    sh[0] = pb;
    gmeta[g] = pb;
    if (g == NG - 1) gmeta[NG] = pb + ((hist[g] + 31u) & ~31u);
  }
  __syncthreads();
  unsigned int run = sh[0];
  // pad-slot pre-fill + tilegid for this graph
  {
    unsigned int cnt = hist[g];
    unsigned int pe = (cnt + 31u) & ~31u;
    for (unsigned int i = cnt + t; i < pe; i += 256){
      ecn[run + i] = 0; ern[run + i] = 0; eorig[run + i] = -1;
    }
    unsigned int nt = pe >> 5, tb = run >> 5;
    for (unsigned int i = t; i < nt; i += 256) tilegid[tb + i] = g;
  }
  int lo = (int)sh[1], hi = (int)sh[2];
  int wid = t >> 6;
  for (int base = lo; base < hi; base += 256){
    int i = base + t;
    unsigned int v = (i < hi) ? nodeh[i] : 0u;
    unsigned int x = v;
    #pragma unroll
    for (int d = 1; d < 64; d <<= 1){
      unsigned int y = __shfl_up(x, d);
      if ((t & 63) >= d) x += y;
    }
    if ((t & 63) == 63) wtot[wid] = x;
    __syncthreads();
    unsigned int woff = 0;
    #pragma unroll
    for (int wb = 0; wb < 4; ++wb) if (wb < wid) woff += wtot[wb];
    if (i < hi){
      unsigned int st = run + woff + x - v;
      ncursor[i] = st;
      for (unsigned int j = 0; j < v; ++j) ecn[st + j] = i;   // coalesced-ish fill
    }
    run += wtot[0] + wtot[1] + wtot[2] + wtot[3];
    __syncthreads();
  }
}

// scatter: p sorted by col node (=> by graph), graph segments padded to x32.
// Writes {rn} and {orig} to two dense 4B arrays (cn comes from kscan's ecn fill).
__global__ void kscatter(const int* __restrict__ ei, int E,
                         unsigned int* __restrict__ ncursor,
                         int* __restrict__ ern, int* __restrict__ eorig){
  int idx = blockIdx.x * 256 + threadIdx.x;
  for (int e = idx; e < E; e += gridDim.x * 256){
    int cn = ei[e], rn = ei[E + e];
    unsigned int p = atomicAdd(&ncursor[cn], 1u);
    ern[p] = rn; eorig[p] = e;
  }
}

// ---------------- GEMM1: PQ[N,512] = emb[N,64] @ W1cat[64,512] (+b1 on P cols) --------------
// One wave per 16-row m-tile; emb read as f32 and converted in-register (no embb pass).
__global__ void __launch_bounds__(256) kgemm1(const float* __restrict__ emb,
    const unsigned short* __restrict__ WcF, const float* __restrict__ b1,
    unsigned short* __restrict__ PQb, int Nn){
  int wave = threadIdx.x >> 6, lane = threadIdx.x & 63;
  int quad = lane >> 4, l15 = lane & 15;
  int tm = blockIdx.x * 4 + wave;
  int tmmax = (Nn + 15) >> 4;
  if (tm >= tmmax) return;
  int m = tm * 16 + l15; if (m >= Nn) m = Nn - 1;
  const float* er = emb + (size_t)m * 64 + quad * 8;
  float4 f0 = *(const float4*)er,        f1 = *(const float4*)(er + 4);
  float4 f2 = *(const float4*)(er + 32), f3 = *(const float4*)(er + 36);
  ABFrag a0, a1;
  a0.q.x = pk2(f0.x, f0.y); a0.q.y = pk2(f0.z, f0.w);
  a0.q.z = pk2(f1.x, f1.y); a0.q.w = pk2(f1.z, f1.w);
  a1.q.x = pk2(f2.x, f2.y); a1.q.y = pk2(f2.z, f2.w);
  a1.q.z = pk2(f3.x, f3.y); a1.q.w = pk2(f3.z, f3.w);
  int rowbase = tm * 16 + quad * 4;
  #pragma unroll 4
  for (int tn = 0; tn < 32; ++tn){
    ABFrag b0, b1f;
    b0.q  = *(const uint4*)(WcF + ((size_t)(tn * 2 + 0) * 64 + lane) * 8);
    b1f.q = *(const uint4*)(WcF + ((size_t)(tn * 2 + 1) * 64 + lane) * 8);
    f32x4 acc = {0.f, 0.f, 0.f, 0.f};
    acc = __builtin_amdgcn_mfma_f32_16x16x32_bf16(a0.v, b0.v, acc, 0, 0, 0);
    acc = __builtin_amdgcn_mfma_f32_16x16x32_bf16(a1.v, b1f.v, acc, 0, 0, 0);
    int col = tn * 16 + l15;
    float bias = (col < 256) ? b1[col] : 0.0f;
    #pragma unroll
    for (int r = 0; r < 4; ++r){
      int rowg = rowbase + r;
      if (rowg < Nn) PQb[(size_t)rowg * 512 + col] = f2b(acc[r] + bias);
    }
  }
}

// ------- stats over y1 = P[col]+Q[row], per-node decomposition -----------------------------
// Four quarter-waves process four edges concurrently (16 Q-row loads in flight at
// unroll 4); each lane covers 16 channels via two 16B loads (16 lanes x 32B = full row).
// Quarters combined per node by shfl_xor(16/32) butterfly; remainder by quarters < rem.
__global__ void __launch_bounds__(256) kstats1(const unsigned short* __restrict__ PQb,
    const int* __restrict__ ern, const int* __restrict__ batch,
    const unsigned int* __restrict__ ncursor, const unsigned int* __restrict__ nodeh,
    float* __restrict__ sum1, float* __restrict__ sq1, int N){
  __shared__ float lsum[4][256];
  __shared__ float lsq[4][256];
  int tid = threadIdx.x;
  for (int i = tid; i < 4 * 256; i += 256){ ((float*)lsum)[i] = 0.f; ((float*)lsq)[i] = 0.f; }
  __syncthreads();
  int base = blockIdx.x * 32;
  int gfirst = batch[base];
  int wid = tid >> 6, lane = tid & 63;
  int quarter = lane >> 4, l15 = lane & 15;
  int c16 = l15 * 16;                    // 16-channel slice (2 x 16B)
  float T1[16], T2[16];
  #pragma unroll
  for (int t = 0; t < 16; ++t){ T1[t] = 0.f; T2[t] = 0.f; }
  int curg = -1;
  auto flushT = [&](){
    if (curg >= 0){
      if (quarter == 0){
        unsigned slot = (unsigned)(curg - gfirst);
        if (slot < 4u){
          #pragma unroll
          for (int t = 0; t < 16; ++t){
            atomicAdd(&lsum[slot][c16 + t], T1[t]);
            atomicAdd(&lsq[slot][c16 + t], T2[t]);
          }
        } else {
          #pragma unroll
          for (int t = 0; t < 16; ++t){
            atomicAdd(&sum1[curg * 256 + c16 + t], T1[t]);
            atomicAdd(&sq1[curg * 256 + c16 + t], T2[t]);
          }
        }
      }
      #pragma unroll
      for (int t = 0; t < 16; ++t){ T1[t] = 0.f; T2[t] = 0.f; }
    }
  };
  for (int i = 0; i < 8; ++i){
    int n = base + wid + i * 4;
    if (n >= N) break;
    int g = batch[n];                 // uniform address -> broadcast
    unsigned int cnt = nodeh[n];
    if (g != curg){ flushT(); curg = g; }
    if (!cnt) continue;
    unsigned int start = ncursor[n] - cnt;   // ncursor holds end after kscatter
    U8 pv0, pv1;
    pv0.q = *(const uint4*)(PQb + (size_t)n * 512 + c16);
    pv1.q = *(const uint4*)(PQb + (size_t)n * 512 + c16 + 8);
    float S1[16], S2[16];
    #pragma unroll
    for (int t = 0; t < 16; ++t){ S1[t] = 0.f; S2[t] = 0.f; }
    for (unsigned int jb = 0; jb < cnt; jb += 64){
      int jn = (int)min(64u, cnt - jb);
      int rnv = (lane < jn) ? __builtin_nontemporal_load(&ern[start + jb + (unsigned)lane]) : 0;
      int jj = 0;
      #pragma unroll 4
      for (; jj + 4 <= jn; jj += 4){
        int rn = __shfl(rnv, jj + quarter);     // quarter q -> edge jj+q
        U8 q0, q1;
        q0.q = *(const uint4*)(PQb + (size_t)rn * 512 + 256 + c16);
        q1.q = *(const uint4*)(PQb + (size_t)rn * 512 + 256 + c16 + 8);
        #pragma unroll
        for (int t = 0; t < 8; ++t){
          float qa = b2f(q0.u[t]);
          S1[t] += qa; S2[t] = fmaf(qa, qa, S2[t]);
          float qb = b2f(q1.u[t]);
          S1[8 + t] += qb; S2[8 + t] = fmaf(qb, qb, S2[8 + t]);
        }
      }
      int rem = jn - jj;
      if (rem > 0){
        int rn = __shfl(rnv, jj + (quarter < rem ? quarter : 0));
        if (quarter < rem){
          U8 q0, q1;
          q0.q = *(const uint4*)(PQb + (size_t)rn * 512 + 256 + c16);
          q1.q = *(const uint4*)(PQb + (size_t)rn * 512 + 256 + c16 + 8);
          #pragma unroll
          for (int t = 0; t < 8; ++t){
            float qa = b2f(q0.u[t]);
            S1[t] += qa; S2[t] = fmaf(qa, qa, S2[t]);
            float qb = b2f(q1.u[t]);
            S1[8 + t] += qb; S2[8 + t] = fmaf(qb, qb, S2[8 + t]);
          }
        }
      }
    }
    // combine quarters (lanes l, l^16, l^32, l^48 cover the same channels)
    #pragma unroll
    for (int t = 0; t < 16; ++t){
      S1[t] += __shfl_xor(S1[t], 16);
      S1[t] += __shfl_xor(S1[t], 32);
      S2[t] += __shfl_xor(S2[t], 16);
      S2[t] += __shfl_xor(S2[t], 32);
    }
    float fc = (float)cnt;
    #pragma unroll
    for (int t = 0; t < 8; ++t){
      float pa = b2f(pv0.u[t]);
      T1[t] += fmaf(fc, pa, S1[t]);
      T2[t] += fmaf(fmaf(fc, pa, 2.f * S1[t]), pa, S2[t]);
      float pb = b2f(pv1.u[t]);
      T1[8 + t] += fmaf(fc, pb, S1[8 + t]);
      T2[8 + t] += fmaf(fmaf(fc, pb, 2.f * S1[8 + t]), pb, S2[8 + t]);
    }
  }
  flushT();
  __syncthreads();
  for (int i = tid; i < 4 * 256; i += 256){
    int slot = i >> 8, ch = i & 255;
    float vs = lsum[slot][ch], vq = lsq[slot][ch];
    if (vs != 0.f || vq != 0.f){
      int g = gfirst + slot;
      atomicAdd(&sum1[g * 256 + ch], vs);
      atomicAdd(&sq1[g * 256 + ch], vq);
    }
  }
}

__global__ void kfin(const float* __restrict__ sum, const float* __restrict__ sq,
                     const unsigned int* __restrict__ hist,
                     float* __restrict__ meanA, float* __restrict__ rstdA, int C){
  int i = blockIdx.x * blockDim.x + threadIdx.x;
  if (i >= NG * C) return;
  int g = i / C;
  float cnt = fmaxf((float)hist[g], 1.0f);
  float m = sum[i] / cnt;
  float v = sq[i] / cnt - m * m;
  meanA[i] = m;
  rstdA[i] = rsqrtf(fmaxf(v, 0.f) + EPSI);
}

// ------- pre-normalize P half in place: P'[n] = (P[n] - mean[g]) * rstd[g], g = batch[n] ----
__global__ void __launch_bounds__(256) knorm1(unsigned short* __restrict__ PQb,
    const int* __restrict__ batch, const float* __restrict__ mean1,
    const float* __restrict__ rstd1, int N){
  int idx = blockIdx.x * 256 + threadIdx.x;
  if (idx >= N * 32) return;
  int n = idx >> 5, c8 = (idx & 31) * 8;
  int g = batch[n];
  unsigned short* pp = PQb + (size_t)n * 512 + c8;
  U8 pu; pu.q = *(const uint4*)pp;
  const float* mg = mean1 + g * 256 + c8;
  const float* rg = rstd1 + g * 256 + c8;
  float4 m0 = *(const float4*)mg, m1 = *(const float4*)(mg + 4);
  float4 r0 = *(const float4*)rg, r1 = *(const float4*)(rg + 4);
  U8 o;
  o.q.x = pk2((b2f(pu.u[0]) - m0.x) * r0.x, (b2f(pu.u[1]) - m0.y) * r0.y);
  o.q.y = pk2((b2f(pu.u[2]) - m0.z) * r0.z, (b2f(pu.u[3]) - m0.w) * r0.w);
  o.q.z = pk2((b2f(pu.u[4]) - m1.x) * r1.x, (b2f(pu.u[5]) - m1.y) * r1.y);
  o.q.w = pk2((b2f(pu.u[6]) - m1.z) * r1.z, (b2f(pu.u[7]) - m1.w) * r1.w);
  *(uint4*)pp = o.q;
}

// ------- fused: h1 = relu(P'[c] + Q[r]*rstd) -> GEMM2 -> y2 + fused stats2 ------------------
// Single-graph 32-edge tiles (padded). Barrier-free main loop; per-tile uniform rstd;
// R6-proven inner schedule; R8 full-line store order; XCD-contiguous swizzle.
// NOTE: mr-fusion (knorm1 elimination) is POISON here -- twice measured (R7, R13) to
// trigger y2b write-allocate churn (+100MB FETCH/WRITE). Keep rstd-only + knorm1.
__global__ void __launch_bounds__(256, 5) kmain(const unsigned short* __restrict__ PQb,
    const unsigned short* __restrict__ W2F,
    const int* __restrict__ ecn, const int* __restrict__ ern,
    const int* __restrict__ tilegid,
    const float* __restrict__ rstd1, const float* __restrict__ b2,
    const unsigned int* __restrict__ hist, const unsigned int* __restrict__ gmeta,
    unsigned short* __restrict__ y2b, float* __restrict__ sum2, float* __restrict__ sq2){
  __shared__ unsigned short Blds[4 * 8 * 64 * 8];  // 32 KiB, same layout as W2F
  {
    const uint4* src = (const uint4*)W2F;
    uint4* dst = (uint4*)Blds;
    for (int i = threadIdx.x; i < 2048; i += 256) dst[i] = src[i];
  }
  __syncthreads();  // only barrier in the kernel
  int wave = threadIdx.x >> 6, lane = threadIdx.x & 63;
  int quad = lane >> 4, l15 = lane & 15;
  float b2v[4];
  #pragma unroll
  for (int cg = 0; cg < 4; ++cg) b2v[cg] = b2[cg * 16 + l15];
  int ntiles = (int)(gmeta[NG] >> 5);
  int nw = gridDim.x * 4;
  int bid = blockIdx.x;
  int nblk = gridDim.x;
  int swz = ((nblk & 7) == 0) ? ((bid & 7) * (nblk >> 3) + (bid >> 3)) : bid;
  for (int t = swz * 4 + wave; t < ntiles; t += nw){
    int p0 = t * 32;
    int g = __builtin_amdgcn_readfirstlane(tilegid[t]);
    int cn0 = __builtin_nontemporal_load(&ecn[p0 + l15]);
    int cn1 = __builtin_nontemporal_load(&ecn[p0 + 16 + l15]);
    int rn0 = __builtin_nontemporal_load(&ern[p0 + l15]);
    int rn1 = __builtin_nontemporal_load(&ern[p0 + 16 + l15]);
    const unsigned short* pp0 = PQb + (size_t)cn0 * 512 + quad * 8;
    const unsigned short* qq0 = PQb + (size_t)rn0 * 512 + 256 + quad * 8;
    const unsigned short* pp1 = PQb + (size_t)cn1 * 512 + quad * 8;
    const unsigned short* qq1 = PQb + (size_t)rn1 * 512 + 256 + quad * 8;
    const float* rr = rstd1 + g * 256 + quad * 8;  // uniform per tile (broadcast loads)
    f32x4 acc[8];  // [sub*4 + cg]
    #pragma unroll
    for (int i = 0; i < 8; ++i){ acc[i][0]=0.f; acc[i][1]=0.f; acc[i][2]=0.f; acc[i][3]=0.f; }
    #pragma unroll 2
    for (int ks = 0; ks < 8; ++ks){
      U8 pu0, qu0, pu1, qu1;
      pu0.q = *(const uint4*)(pp0 + ks * 32);
      qu0.q = *(const uint4*)(qq0 + ks * 32);
      pu1.q = *(const uint4*)(pp1 + ks * 32);
      qu1.q = *(const uint4*)(qq1 + ks * 32);
      float4 ra = *(const float4*)(rr + ks * 32);
      float4 rb = *(const float4*)(rr + ks * 32 + 4);
      ABFrag a0, a1;
      a0.q.x = pk2(fmaxf(0.f, b2f(pu0.u[0]) + b2f(qu0.u[0]) * ra.x),
                   fmaxf(0.f, b2f(pu0.u[1]) + b2f(qu0.u[1]) * ra.y));
      a0.q.y = pk2(fmaxf(0.f, b2f(pu0.u[2]) + b2f(qu0.u[2]) * ra.z),
                   fmaxf(0.f, b2f(pu0.u[3]) + b2f(qu0.u[3]) * ra.w));
      a0.q.z = pk2(fmaxf(0.f, b2f(pu0.u[4]) + b2f(qu0.u[4]) * rb.x),
                   fmaxf(0.f, b2f(pu0.u[5]) + b2f(qu0.u[5]) * rb.y));
      a0.q.w = pk2(fmaxf(0.f, b2f(pu0.u[6]) + b2f(qu0.u[6]) * rb.z),
                   fmaxf(0.f, b2f(pu0.u[7]) + b2f(qu0.u[7]) * rb.w));
      a1.q.x = pk2(fmaxf(0.f, b2f(pu1.u[0]) + b2f(qu1.u[0]) * ra.x),
                   fmaxf(0.f, b2f(pu1.u[1]) + b2f(qu1.u[1]) * ra.y));
      a1.q.y = pk2(fmaxf(0.f, b2f(pu1.u[2]) + b2f(qu1.u[2]) * ra.z),
                   fmaxf(0.f, b2f(pu1.u[3]) + b2f(qu1.u[3]) * ra.w));
      a1.q.z = pk2(fmaxf(0.f, b2f(pu1.u[4]) + b2f(qu1.u[4]) * rb.x),
                   fmaxf(0.f, b2f(pu1.u[5]) + b2f(qu1.u[5]) * rb.y));
      a1.q.w = pk2(fmaxf(0.f, b2f(pu1.u[6]) + b2f(qu1.u[6]) * rb.z),
                   fmaxf(0.f, b2f(pu1.u[7]) + b2f(qu1.u[7]) * rb.w));
      #pragma unroll
      for (int cg = 0; cg < 4; ++cg){
        ABFrag b;
        b.q = *(const uint4*)&Blds[((cg * 8 + ks) * 64 + lane) * 8];
        acc[cg]     = __builtin_amdgcn_mfma_f32_16x16x32_bf16(a0.v, b.v, acc[cg], 0, 0, 0);
        acc[4 + cg] = __builtin_amdgcn_mfma_f32_16x16x32_bf16(a1.v, b.v, acc[4 + cg], 0, 0, 0);
      }
    }
    // epilogue stage 1: y2b stores, full 128B row assembled by 4 consecutive 32B chunks
    #pragma unroll
    for (int sub = 0; sub < 2; ++sub)
      #pragma unroll
      for (int r = 0; r < 4; ++r){
        int el = sub * 16 + quad * 4 + r;
        size_t rowo = (size_t)(p0 + el) * 64 + l15;
        #pragma unroll
        for (int cg = 0; cg < 4; ++cg)
          y2b[rowo + cg * 16] = f2b(acc[sub * 4 + cg][r] + b2v[cg]);
      }
    // epilogue stage 2: fused stats2 (f32, pads masked via real-count)
    int nl = (int)gmeta[g] + (int)hist[g] - p0;  // # real edges in this tile (may exceed 32)
    #pragma unroll
    for (int cg = 0; cg < 4; ++cg){
      float s = 0.f, qs = 0.f;
      #pragma unroll
      for (int sub = 0; sub < 2; ++sub)
        #pragma unroll
        for (int r = 0; r < 4; ++r){
          int el = sub * 16 + quad * 4 + r;
          if (el < nl){
            float y = acc[sub * 4 + cg][r] + b2v[cg];
            s += y; qs = fmaf(y, y, qs);
          }
        }
      s  += __shfl_xor(s, 16);  s  += __shfl_xor(s, 32);
      qs += __shfl_xor(qs, 16); qs += __shfl_xor(qs, 32);
      if (quad == 0){
        atomicAdd(&sum2[g * 64 + cg * 16 + l15], s);
        atomicAdd(&sq2[g * 64 + cg * 16 + l15], qs);
      }
    }
  }
}

// ------- final: norm+ReLU L2 -> GEMV W3 -> scatter; 8 lanes per edge + shuffle reduce -------
__global__ void kfinal(const unsigned short* __restrict__ y2b,
                       const int* __restrict__ eorig, const int* __restrict__ tilegid,
                       const unsigned int* __restrict__ gmeta,
                       const float* __restrict__ mean2, const float* __restrict__ rstd2,
                       const float* __restrict__ W3, const float* __restrict__ b3,
                       float* __restrict__ out){
  int EP = (int)gmeta[NG];
  int sub = threadIdx.x & 7;
  int c8 = sub * 8;
  float w3r[8];
  #pragma unroll
  for (int t = 0; t < 8; ++t) w3r[t] = W3[c8 + t];
  float b3v = b3[0];
  int step = (gridDim.x * blockDim.x) >> 3;
  for (int i = (blockIdx.x * blockDim.x + threadIdx.x) >> 3; i < EP; i += step){
    int orig = __builtin_nontemporal_load(&eorig[i]);
    int gz = tilegid[i >> 5];
    U8 yv; yv.e = __builtin_nontemporal_load((const u32x4*)(y2b + (size_t)i * 64 + c8));
    const float* mg = mean2 + gz * 64 + c8;
    const float* rg = rstd2 + gz * 64 + c8;
    float4 m0 = *(const float4*)mg, m1 = *(const float4*)(mg + 4);
    float4 r0 = *(const float4*)rg, r1 = *(const float4*)(rg + 4);
    float a = 0.f;
    a += fmaxf(0.f, (b2f(yv.u[0]) - m0.x) * r0.x) * w3r[0];
    a += fmaxf(0.f, (b2f(yv.u[1]) - m0.y) * r0.y) * w3r[1];
    a += fmaxf(0.f, (b2f(yv.u[2]) - m0.z) * r0.z) * w3r[2];
    a += fmaxf(0.f, (b2f(yv.u[3]) - m0.w) * r0.w) * w3r[3];
    a += fmaxf(0.f, (b2f(yv.u[4]) - m1.x) * r1.x) * w3r[4];
    a += fmaxf(0.f, (b2f(yv.u[5]) - m1.y) * r1.y) * w3r[5];
    a += fmaxf(0.f, (b2f(yv.u[6]) - m1.z) * r1.z) * w3r[6];
    a += fmaxf(0.f, (b2f(yv.u[7]) - m1.w) * r1.w) * w3r[7];
    a += __shfl_xor(a, 1);
    a += __shfl_xor(a, 2);
    a += __shfl_xor(a, 4);
    if (sub == 0 && orig >= 0) out[orig] = a + b3v;
  }
}

extern "C" void kernel_launch(void* const* d_in, const int* in_sizes, int n_in,
                              void* d_out, int out_size, void* d_ws, size_t ws_size,
                              hipStream_t stream){
  const float* emb  = (const float*)d_in[0];
  const int*   ei   = (const int*)d_in[1];
  const int*   batch= (const int*)d_in[2];
  const float* W1   = (const float*)d_in[3];
  const float* b1   = (const float*)d_in[4];
  const float* W2   = (const float*)d_in[5];
  const float* b2   = (const float*)d_in[6];
  const float* W3   = (const float*)d_in[7];
  const float* b3   = (const float*)d_in[8];
  int N = in_sizes[0] / 64;
  int E = in_sizes[1] / 2;
  int EPMAX = E + NG * 32;   // upper bound on padded edge count
  float* out = (float*)d_out;

  char* w = (char*)d_ws;
  size_t off = 0;
  auto nxt = [&](size_t bytes) -> char* {
    char* p = w + off;
    off = (off + bytes + 255) & ~(size_t)255;
    return p;
  };
  unsigned short* WcF  = (unsigned short*)nxt(32 * 2 * 64 * 8 * 2);
  unsigned short* W2F  = (unsigned short*)nxt(4 * 8 * 64 * 8 * 2);
  unsigned short* PQb  = (unsigned short*)nxt((size_t)N * 512 * 2);
  unsigned short* y2b  = (unsigned short*)nxt((size_t)EPMAX * 64 * 2);
  int* ecn   = (int*)nxt((size_t)EPMAX * 4);
  int* ern   = (int*)nxt((size_t)EPMAX * 4);
  int* eorig = (int*)nxt((size_t)EPMAX * 4);
  int* tilegid = (int*)nxt((size_t)(EPMAX / 32 + 1) * 4);
  float* mean1 = (float*)nxt(NG * 256 * 4);
  float* rstd1 = (float*)nxt(NG * 256 * 4);
  float* mean2 = (float*)nxt(NG * 64 * 4);
  float* rstd2 = (float*)nxt(NG * 64 * 4);
  unsigned int* ncursor = (unsigned int*)nxt((size_t)N * 4);
  unsigned int* gmeta   = (unsigned int*)nxt((NG + 1) * 4);
  // zero-init region (contiguous, one memset)
  char* zbase = w + off;
  unsigned int* hist  = (unsigned int*)nxt(NG * 4);
  unsigned int* nodeh = (unsigned int*)nxt((size_t)N * 4);
  float* sum1 = (float*)nxt(NG * 256 * 4);
  float* sq1  = (float*)nxt(NG * 256 * 4);
  float* sum2 = (float*)nxt(NG * 64 * 4);
  float* sq2  = (float*)nxt(NG * 64 * 4);
  size_t zbytes = (size_t)((w + off) - zbase);
  hipMemsetAsync(zbase, 0, zbytes, stream);

  kprep<<<1024, 256, 0, stream>>>(W1, W2, ei, WcF, W2F, nodeh, E);
  khist<<<64, 256, 0, stream>>>(nodeh, batch, hist, N);
  kscan<<<NG, 256, 0, stream>>>(nodeh, hist, batch, ncursor, gmeta,
                                ecn, ern, eorig, tilegid, N);
  kscatter<<<2048, 256, 0, stream>>>(ei, E, ncursor, ern, eorig);
  {
    int tmmax = (N + 15) / 16;
    kgemm1<<<(tmmax + 3) / 4, 256, 0, stream>>>(emb, WcF, b1, PQb, N);
  }
  kstats1<<<(N + 31) / 32, 256, 0, stream>>>(PQb, ern, batch, ncursor, nodeh, sum1, sq1, N);
  kfin<<<(NG * 256 + 255) / 256, 256, 0, stream>>>(sum1, sq1, hist, mean1, rstd1, 256);
  knorm1<<<(N * 32 + 255) / 256, 256, 0, stream>>>(PQb, batch, mean1, rstd1, N);
  kmain<<<2048, 256, 0, stream>>>(PQb, W2F, ecn, ern, tilegid, rstd1, b2, hist, gmeta,
                                  y2b, sum2, sq2);
  kfin<<<(NG * 64 + 255) / 256, 256, 0, stream>>>(sum2, sq2, hist, mean2, rstd2, 64);
  kfinal<<<2048, 256, 0, stream>>>(y2b, eorig, tilegid, gmeta, mean2, rstd2, W3, b3, out);
}

// Round 17
// 429.674 us; speedup vs baseline: 1.0599x; 1.0599x over previous
//
#include <hip/hip_runtime.h>
#include <hip/hip_bf16.h>
#include <stdint.h>

#define NG 128
#define EPSI 1e-5f

typedef __attribute__((ext_vector_type(8))) __bf16 bf16x8;
typedef __attribute__((ext_vector_type(4))) float f32x4;
typedef unsigned int u32x4 __attribute__((ext_vector_type(4)));

union ABFrag { bf16x8 v; unsigned short u[8]; uint4 q; };
union U8 { uint4 q; unsigned short u[8]; u32x4 e; };

__device__ __forceinline__ float b2f(unsigned short u){
  union { unsigned int i; float f; } v; v.i = ((unsigned int)u) << 16; return v.f;
}
__device__ __forceinline__ unsigned short f2b(float f){
  union { float f; unsigned int i; } v; v.f = f;
  unsigned int r = v.i + 0x7fffu + ((v.i >> 16) & 1u);
  return (unsigned short)(r >> 16);
}
// pack 2 f32 -> 2 bf16 (RNE), lo in bits[15:0], hi in bits[31:16]
__device__ __forceinline__ unsigned int pk2(float lo, float hi){
  unsigned int r;
  asm("v_cvt_pk_bf16_f32 %0, %1, %2" : "=v"(r) : "v"(lo), "v"(hi));
  return r;
}

// ---------------- prep: W1/W2 bf16 conversions (frag order), node hist ----------------
__global__ void kprep(const float* __restrict__ W1, const float* __restrict__ W2,
                      const int* __restrict__ ei,
                      unsigned short* __restrict__ WcF, unsigned short* __restrict__ W2F,
                      unsigned int* __restrict__ nodeh, int E){
  int idx = blockIdx.x * 256 + threadIdx.x;
  int stride = gridDim.x * 256;
  for (int i = idx; i < 32 * 2 * 64 * 8; i += stride){
    int j = i & 7, lane = (i >> 3) & 63, ks = (i >> 9) & 1, tn = i >> 10;
    int quad = lane >> 4, l15 = lane & 15;
    int k = ks * 32 + quad * 8 + j;
    int n = tn * 16 + l15;
    float wv = (n < 256) ? W1[k * 256 + n] : W1[(k + 64) * 256 + (n - 256)];
    WcF[i] = f2b(wv);
  }
  for (int i = idx; i < 4 * 8 * 64 * 8; i += stride){
    int j = i & 7, lane = (i >> 3) & 63, ks = (i >> 9) & 7, w = i >> 12;
    int quad = lane >> 4, l15 = lane & 15;
    W2F[i] = f2b(W2[(ks * 32 + quad * 8 + j) * 64 + w * 16 + l15]);
  }
  for (int e = idx; e < E; e += stride)
    atomicAdd(&nodeh[ei[e]], 1u);
}

// --- graph hist from node hist: hist[g] = sum nodeh[n] for n in g (batch sorted) ---
__global__ void khist(const unsigned int* __restrict__ nodeh, const int* __restrict__ batch,
                      unsigned int* __restrict__ hist, int N){
  __shared__ unsigned int h[NG];
  for (int i = threadIdx.x; i < NG; i += 256) h[i] = 0;
  __syncthreads();
  int idx = blockIdx.x * 256 + threadIdx.x;
  for (int i = idx; i < N; i += gridDim.x * 256)
    atomicAdd(&h[batch[i]], nodeh[i]);
  __syncthreads();
  for (int i = threadIdx.x; i < NG; i += 256)
    if (h[i]) atomicAdd(&hist[i], h[i]);
}

// --- scan: one block per graph. Computes padded-base prefix (pbase) from hist,
//     binary-searches this graph's node range, exclusive-scans nodeh into ncursor,
//     fills ecn coalesced (node id per edge slot), pre-fills pads, writes tilegid. ---
__global__ void __launch_bounds__(256) kscan(const unsigned int* __restrict__ nodeh,
                      const unsigned int* __restrict__ hist,
                      const int* __restrict__ batch,
                      unsigned int* __restrict__ ncursor,
                      unsigned int* __restrict__ gmeta,
                      int* __restrict__ ecn, int* __restrict__ ern,
                      int* __restrict__ eorig, int* __restrict__ tilegid, int N){
  __shared__ unsigned int sh[3];     // pbase, lo, hi
  __shared__ unsigned int wtot[4];
  int g = blockIdx.x;
  int t = threadIdx.x;
  // padded-count prefix over graphs < g (redundant per block; trivial work)
  unsigned int part = 0;
  for (int i = t; i < g; i += 256) part += (hist[i] + 31u) & ~31u;
  #pragma unroll
  for (int d = 1; d < 64; d <<= 1) part += __shfl_xor(part, d);
  if ((t & 63) == 0) wtot[t >> 6] = part;
  // node range via binary search on sorted batch
  if (t == 64 || t == 65){
    int target = g + (t - 64);
    int lo = 0, hi = N;
    while (lo < hi){ int mid = (lo + hi) >> 1; if (batch[mid] < target) lo = mid + 1; else hi = mid; }
    sh[1 + (t - 64)] = lo;
  }
  __syncthreads();
  if (t == 0){
    unsigned int pb = wtot[0] + wtot[1] + wtot[2] + wtot[3];
    sh[0] = pb;
    gmeta[g] = pb;
    if (g == NG - 1) gmeta[NG] = pb + ((hist[g] + 31u) & ~31u);
  }
  __syncthreads();
  unsigned int run = sh[0];
  // pad-slot pre-fill + tilegid for this graph
  {
    unsigned int cnt = hist[g];
    unsigned int pe = (cnt + 31u) & ~31u;
    for (unsigned int i = cnt + t; i < pe; i += 256){
      ecn[run + i] = 0; ern[run + i] = 0; eorig[run + i] = -1;
    }
    unsigned int nt = pe >> 5, tb = run >> 5;
    for (unsigned int i = t; i < nt; i += 256) tilegid[tb + i] = g;
  }
  int lo = (int)sh[1], hi = (int)sh[2];
  int wid = t >> 6;
  for (int base = lo; base < hi; base += 256){
    int i = base + t;
    unsigned int v = (i < hi) ? nodeh[i] : 0u;
    unsigned int x = v;
    #pragma unroll
    for (int d = 1; d < 64; d <<= 1){
      unsigned int y = __shfl_up(x, d);
      if ((t & 63) >= d) x += y;
    }
    if ((t & 63) == 63) wtot[wid] = x;
    __syncthreads();
    unsigned int woff = 0;
    #pragma unroll
    for (int wb = 0; wb < 4; ++wb) if (wb < wid) woff += wtot[wb];
    if (i < hi){
      unsigned int st = run + woff + x - v;
      ncursor[i] = st;
      for (unsigned int j = 0; j < v; ++j) ecn[st + j] = i;   // coalesced-ish fill
    }
    run += wtot[0] + wtot[1] + wtot[2] + wtot[3];
    __syncthreads();
  }
}

// scatter: p sorted by col node (=> by graph), graph segments padded to x32.
// Writes {rn} and {orig} to two dense 4B arrays (cn comes from kscan's ecn fill).
__global__ void kscatter(const int* __restrict__ ei, int E,
                         unsigned int* __restrict__ ncursor,
                         int* __restrict__ ern, int* __restrict__ eorig){
  int idx = blockIdx.x * 256 + threadIdx.x;
  for (int e = idx; e < E; e += gridDim.x * 256){
    int cn = ei[e], rn = ei[E + e];
    unsigned int p = atomicAdd(&ncursor[cn], 1u);
    ern[p] = rn; eorig[p] = e;
  }
}

// ---------------- GEMM1: PQ[N,512] = emb[N,64] @ W1cat[64,512] (+b1 on P cols) --------------
// One wave per 16-row m-tile; emb read as f32 and converted in-register (no embb pass).
__global__ void __launch_bounds__(256) kgemm1(const float* __restrict__ emb,
    const unsigned short* __restrict__ WcF, const float* __restrict__ b1,
    unsigned short* __restrict__ PQb, int Nn){
  int wave = threadIdx.x >> 6, lane = threadIdx.x & 63;
  int quad = lane >> 4, l15 = lane & 15;
  int tm = blockIdx.x * 4 + wave;
  int tmmax = (Nn + 15) >> 4;
  if (tm >= tmmax) return;
  int m = tm * 16 + l15; if (m >= Nn) m = Nn - 1;
  const float* er = emb + (size_t)m * 64 + quad * 8;
  float4 f0 = *(const float4*)er,        f1 = *(const float4*)(er + 4);
  float4 f2 = *(const float4*)(er + 32), f3 = *(const float4*)(er + 36);
  ABFrag a0, a1;
  a0.q.x = pk2(f0.x, f0.y); a0.q.y = pk2(f0.z, f0.w);
  a0.q.z = pk2(f1.x, f1.y); a0.q.w = pk2(f1.z, f1.w);
  a1.q.x = pk2(f2.x, f2.y); a1.q.y = pk2(f2.z, f2.w);
  a1.q.z = pk2(f3.x, f3.y); a1.q.w = pk2(f3.z, f3.w);
  int rowbase = tm * 16 + quad * 4;
  #pragma unroll 4
  for (int tn = 0; tn < 32; ++tn){
    ABFrag b0, b1f;
    b0.q  = *(const uint4*)(WcF + ((size_t)(tn * 2 + 0) * 64 + lane) * 8);
    b1f.q = *(const uint4*)(WcF + ((size_t)(tn * 2 + 1) * 64 + lane) * 8);
    f32x4 acc = {0.f, 0.f, 0.f, 0.f};
    acc = __builtin_amdgcn_mfma_f32_16x16x32_bf16(a0.v, b0.v, acc, 0, 0, 0);
    acc = __builtin_amdgcn_mfma_f32_16x16x32_bf16(a1.v, b1f.v, acc, 0, 0, 0);
    int col = tn * 16 + l15;
    float bias = (col < 256) ? b1[col] : 0.0f;
    #pragma unroll
    for (int r = 0; r < 4; ++r){
      int rowg = rowbase + r;
      if (rowg < Nn) PQb[(size_t)rowg * 512 + col] = f2b(acc[r] + bias);
    }
  }
}

// ------- stats over y1 = P[col]+Q[row], per-node decomposition -----------------------------
// Two half-waves process two edges concurrently (8 Q-row loads in flight at unroll 4);
// each lane covers 8 channels with one 16B load. Halves xor-reduced per node.
// (R16's quarter-wave variant regressed: VGPR pressure + butterfly overhead. Keep this.)
__global__ void __launch_bounds__(256) kstats1(const unsigned short* __restrict__ PQb,
    const int* __restrict__ ern, const int* __restrict__ batch,
    const unsigned int* __restrict__ ncursor, const unsigned int* __restrict__ nodeh,
    float* __restrict__ sum1, float* __restrict__ sq1, int N){
  __shared__ float lsum[4][256];
  __shared__ float lsq[4][256];
  int tid = threadIdx.x;
  for (int i = tid; i < 4 * 256; i += 256){ ((float*)lsum)[i] = 0.f; ((float*)lsq)[i] = 0.f; }
  __syncthreads();
  int base = blockIdx.x * 32;
  int gfirst = batch[base];
  int wid = tid >> 6, lane = tid & 63;
  int half = lane >> 5, l31 = lane & 31;
  int c8 = l31 * 8;                      // 8-channel slice (16B)
  float T1[8], T2[8];
  #pragma unroll
  for (int t = 0; t < 8; ++t){ T1[t] = 0.f; T2[t] = 0.f; }
  int curg = -1;
  auto flushT = [&](){
    if (curg >= 0){
      if (half == 0){
        unsigned slot = (unsigned)(curg - gfirst);
        if (slot < 4u){
          #pragma unroll
          for (int t = 0; t < 8; ++t){
            atomicAdd(&lsum[slot][c8 + t], T1[t]);
            atomicAdd(&lsq[slot][c8 + t], T2[t]);
          }
        } else {
          #pragma unroll
          for (int t = 0; t < 8; ++t){
            atomicAdd(&sum1[curg * 256 + c8 + t], T1[t]);
            atomicAdd(&sq1[curg * 256 + c8 + t], T2[t]);
          }
        }
      }
      #pragma unroll
      for (int t = 0; t < 8; ++t){ T1[t] = 0.f; T2[t] = 0.f; }
    }
  };
  for (int i = 0; i < 8; ++i){
    int n = base + wid + i * 4;
    if (n >= N) break;
    int g = batch[n];                 // uniform address -> broadcast
    unsigned int cnt = nodeh[n];
    if (g != curg){ flushT(); curg = g; }
    if (!cnt) continue;
    unsigned int start = ncursor[n] - cnt;   // ncursor holds end after kscatter
    U8 pv; pv.q = *(const uint4*)(PQb + (size_t)n * 512 + c8);
    float S1[8], S2[8];
    #pragma unroll
    for (int t = 0; t < 8; ++t){ S1[t] = 0.f; S2[t] = 0.f; }
    for (unsigned int jb = 0; jb < cnt; jb += 64){
      int jn = (int)min(64u, cnt - jb);
      int rnv = (lane < jn) ? __builtin_nontemporal_load(&ern[start + jb + (unsigned)lane]) : 0;
      int jj = 0;
      #pragma unroll 4
      for (; jj + 2 <= jn; jj += 2){
        int rn = __shfl(rnv, jj + half);        // half 0 -> edge jj, half 1 -> edge jj+1
        U8 qv; qv.q = *(const uint4*)(PQb + (size_t)rn * 512 + 256 + c8);
        #pragma unroll
        for (int t = 0; t < 8; ++t){
          float q = b2f(qv.u[t]);
          S1[t] += q; S2[t] = fmaf(q, q, S2[t]);
        }
      }
      if (jj < jn){                             // odd remainder: half 0 only
        int rn = __shfl(rnv, jj);
        if (half == 0){
          U8 qv; qv.q = *(const uint4*)(PQb + (size_t)rn * 512 + 256 + c8);
          #pragma unroll
          for (int t = 0; t < 8; ++t){
            float q = b2f(qv.u[t]);
            S1[t] += q; S2[t] = fmaf(q, q, S2[t]);
          }
        }
      }
    }
    // combine the two halves (lane l and l^32 cover the same channels)
    #pragma unroll
    for (int t = 0; t < 8; ++t){
      S1[t] += __shfl_xor(S1[t], 32);
      S2[t] += __shfl_xor(S2[t], 32);
    }
    float fc = (float)cnt;
    #pragma unroll
    for (int t = 0; t < 8; ++t){
      float p = b2f(pv.u[t]);
      T1[t] += fmaf(fc, p, S1[t]);
      T2[t] += fmaf(fmaf(fc, p, 2.f * S1[t]), p, S2[t]);
    }
  }
  flushT();
  __syncthreads();
  for (int i = tid; i < 4 * 256; i += 256){
    int slot = i >> 8, ch = i & 255;
    float vs = lsum[slot][ch], vq = lsq[slot][ch];
    if (vs != 0.f || vq != 0.f){
      int g = gfirst + slot;
      atomicAdd(&sum1[g * 256 + ch], vs);
      atomicAdd(&sq1[g * 256 + ch], vq);
    }
  }
}

__global__ void kfin(const float* __restrict__ sum, const float* __restrict__ sq,
                     const unsigned int* __restrict__ hist,
                     float* __restrict__ meanA, float* __restrict__ rstdA, int C){
  int i = blockIdx.x * blockDim.x + threadIdx.x;
  if (i >= NG * C) return;
  int g = i / C;
  float cnt = fmaxf((float)hist[g], 1.0f);
  float m = sum[i] / cnt;
  float v = sq[i] / cnt - m * m;
  meanA[i] = m;
  rstdA[i] = rsqrtf(fmaxf(v, 0.f) + EPSI);
}

// ------- pre-normalize P half in place: P'[n] = (P[n] - mean[g]) * rstd[g], g = batch[n] ----
__global__ void __launch_bounds__(256) knorm1(unsigned short* __restrict__ PQb,
    const int* __restrict__ batch, const float* __restrict__ mean1,
    const float* __restrict__ rstd1, int N){
  int idx = blockIdx.x * 256 + threadIdx.x;
  if (idx >= N * 32) return;
  int n = idx >> 5, c8 = (idx & 31) * 8;
  int g = batch[n];
  unsigned short* pp = PQb + (size_t)n * 512 + c8;
  U8 pu; pu.q = *(const uint4*)pp;
  const float* mg = mean1 + g * 256 + c8;
  const float* rg = rstd1 + g * 256 + c8;
  float4 m0 = *(const float4*)mg, m1 = *(const float4*)(mg + 4);
  float4 r0 = *(const float4*)rg, r1 = *(const float4*)(rg + 4);
  U8 o;
  o.q.x = pk2((b2f(pu.u[0]) - m0.x) * r0.x, (b2f(pu.u[1]) - m0.y) * r0.y);
  o.q.y = pk2((b2f(pu.u[2]) - m0.z) * r0.z, (b2f(pu.u[3]) - m0.w) * r0.w);
  o.q.z = pk2((b2f(pu.u[4]) - m1.x) * r1.x, (b2f(pu.u[5]) - m1.y) * r1.y);
  o.q.w = pk2((b2f(pu.u[6]) - m1.z) * r1.z, (b2f(pu.u[7]) - m1.w) * r1.w);
  *(uint4*)pp = o.q;
}

// ------- fused: h1 = relu(P'[c] + Q[r]*rstd) -> GEMM2 -> y2 + fused stats2 ------------------
// Single-graph 32-edge tiles (padded). Barrier-free main loop; per-tile uniform rstd;
// R6-proven inner schedule; R8 full-line store order; XCD-contiguous swizzle.
// NOTE: mr-fusion (knorm1 elimination) is POISON here -- twice measured (R7, R13) to
// trigger y2b write-allocate churn (+100MB FETCH/WRITE). Keep rstd-only + knorm1.
__global__ void __launch_bounds__(256, 5) kmain(const unsigned short* __restrict__ PQb,
    const unsigned short* __restrict__ W2F,
    const int* __restrict__ ecn, const int* __restrict__ ern,
    const int* __restrict__ tilegid,
    const float* __restrict__ rstd1, const float* __restrict__ b2,
    const unsigned int* __restrict__ hist, const unsigned int* __restrict__ gmeta,
    unsigned short* __restrict__ y2b, float* __restrict__ sum2, float* __restrict__ sq2){
  __shared__ unsigned short Blds[4 * 8 * 64 * 8];  // 32 KiB, same layout as W2F
  {
    const uint4* src = (const uint4*)W2F;
    uint4* dst = (uint4*)Blds;
    for (int i = threadIdx.x; i < 2048; i += 256) dst[i] = src[i];
  }
  __syncthreads();  // only barrier in the kernel
  int wave = threadIdx.x >> 6, lane = threadIdx.x & 63;
  int quad = lane >> 4, l15 = lane & 15;
  float b2v[4];
  #pragma unroll
  for (int cg = 0; cg < 4; ++cg) b2v[cg] = b2[cg * 16 + l15];
  int ntiles = (int)(gmeta[NG] >> 5);
  int nw = gridDim.x * 4;
  int bid = blockIdx.x;
  int nblk = gridDim.x;
  int swz = ((nblk & 7) == 0) ? ((bid & 7) * (nblk >> 3) + (bid >> 3)) : bid;
  for (int t = swz * 4 + wave; t < ntiles; t += nw){
    int p0 = t * 32;
    int g = __builtin_amdgcn_readfirstlane(tilegid[t]);
    int cn0 = __builtin_nontemporal_load(&ecn[p0 + l15]);
    int cn1 = __builtin_nontemporal_load(&ecn[p0 + 16 + l15]);
    int rn0 = __builtin_nontemporal_load(&ern[p0 + l15]);
    int rn1 = __builtin_nontemporal_load(&ern[p0 + 16 + l15]);
    const unsigned short* pp0 = PQb + (size_t)cn0 * 512 + quad * 8;
    const unsigned short* qq0 = PQb + (size_t)rn0 * 512 + 256 + quad * 8;
    const unsigned short* pp1 = PQb + (size_t)cn1 * 512 + quad * 8;
    const unsigned short* qq1 = PQb + (size_t)rn1 * 512 + 256 + quad * 8;
    const float* rr = rstd1 + g * 256 + quad * 8;  // uniform per tile (broadcast loads)
    f32x4 acc[8];  // [sub*4 + cg]
    #pragma unroll
    for (int i = 0; i < 8; ++i){ acc[i][0]=0.f; acc[i][1]=0.f; acc[i][2]=0.f; acc[i][3]=0.f; }
    #pragma unroll 2
    for (int ks = 0; ks < 8; ++ks){
      U8 pu0, qu0, pu1, qu1;
      pu0.q = *(const uint4*)(pp0 + ks * 32);
      qu0.q = *(const uint4*)(qq0 + ks * 32);
      pu1.q = *(const uint4*)(pp1 + ks * 32);
      qu1.q = *(const uint4*)(qq1 + ks * 32);
      float4 ra = *(const float4*)(rr + ks * 32);
      float4 rb = *(const float4*)(rr + ks * 32 + 4);
      ABFrag a0, a1;
      a0.q.x = pk2(fmaxf(0.f, b2f(pu0.u[0]) + b2f(qu0.u[0]) * ra.x),
                   fmaxf(0.f, b2f(pu0.u[1]) + b2f(qu0.u[1]) * ra.y));
      a0.q.y = pk2(fmaxf(0.f, b2f(pu0.u[2]) + b2f(qu0.u[2]) * ra.z),
                   fmaxf(0.f, b2f(pu0.u[3]) + b2f(qu0.u[3]) * ra.w));
      a0.q.z = pk2(fmaxf(0.f, b2f(pu0.u[4]) + b2f(qu0.u[4]) * rb.x),
                   fmaxf(0.f, b2f(pu0.u[5]) + b2f(qu0.u[5]) * rb.y));
      a0.q.w = pk2(fmaxf(0.f, b2f(pu0.u[6]) + b2f(qu0.u[6]) * rb.z),
                   fmaxf(0.f, b2f(pu0.u[7]) + b2f(qu0.u[7]) * rb.w));
      a1.q.x = pk2(fmaxf(0.f, b2f(pu1.u[0]) + b2f(qu1.u[0]) * ra.x),
                   fmaxf(0.f, b2f(pu1.u[1]) + b2f(qu1.u[1]) * ra.y));
      a1.q.y = pk2(fmaxf(0.f, b2f(pu1.u[2]) + b2f(qu1.u[2]) * ra.z),
                   fmaxf(0.f, b2f(pu1.u[3]) + b2f(qu1.u[3]) * ra.w));
      a1.q.z = pk2(fmaxf(0.f, b2f(pu1.u[4]) + b2f(qu1.u[4]) * rb.x),
                   fmaxf(0.f, b2f(pu1.u[5]) + b2f(qu1.u[5]) * rb.y));
      a1.q.w = pk2(fmaxf(0.f, b2f(pu1.u[6]) + b2f(qu1.u[6]) * rb.z),
                   fmaxf(0.f, b2f(pu1.u[7]) + b2f(qu1.u[7]) * rb.w));
      #pragma unroll
      for (int cg = 0; cg < 4; ++cg){
        ABFrag b;
        b.q = *(const uint4*)&Blds[((cg * 8 + ks) * 64 + lane) * 8];
        acc[cg]     = __builtin_amdgcn_mfma_f32_16x16x32_bf16(a0.v, b.v, acc[cg], 0, 0, 0);
        acc[4 + cg] = __builtin_amdgcn_mfma_f32_16x16x32_bf16(a1.v, b.v, acc[4 + cg], 0, 0, 0);
      }
    }
    // epilogue stage 1: y2b stores, full 128B row assembled by 4 consecutive 32B chunks
    #pragma unroll
    for (int sub = 0; sub < 2; ++sub)
      #pragma unroll
      for (int r = 0; r < 4; ++r){
        int el = sub * 16 + quad * 4 + r;
        size_t rowo = (size_t)(p0 + el) * 64 + l15;
        #pragma unroll
        for (int cg = 0; cg < 4; ++cg)
          y2b[rowo + cg * 16] = f2b(acc[sub * 4 + cg][r] + b2v[cg]);
      }
    // epilogue stage 2: fused stats2 (f32, pads masked via real-count)
    int nl = (int)gmeta[g] + (int)hist[g] - p0;  // # real edges in this tile (may exceed 32)
    #pragma unroll
    for (int cg = 0; cg < 4; ++cg){
      float s = 0.f, qs = 0.f;
      #pragma unroll
      for (int sub = 0; sub < 2; ++sub)
        #pragma unroll
        for (int r = 0; r < 4; ++r){
          int el = sub * 16 + quad * 4 + r;
          if (el < nl){
            float y = acc[sub * 4 + cg][r] + b2v[cg];
            s += y; qs = fmaf(y, y, qs);
          }
        }
      s  += __shfl_xor(s, 16);  s  += __shfl_xor(s, 32);
      qs += __shfl_xor(qs, 16); qs += __shfl_xor(qs, 32);
      if (quad == 0){
        atomicAdd(&sum2[g * 64 + cg * 16 + l15], s);
        atomicAdd(&sq2[g * 64 + cg * 16 + l15], qs);
      }
    }
  }
}

// ------- final: norm+ReLU L2 -> GEMV W3 -> scatter; 8 lanes per edge + shuffle reduce -------
__global__ void kfinal(const unsigned short* __restrict__ y2b,
                       const int* __restrict__ eorig, const int* __restrict__ tilegid,
                       const unsigned int* __restrict__ gmeta,
                       const float* __restrict__ mean2, const float* __restrict__ rstd2,
                       const float* __restrict__ W3, const float* __restrict__ b3,
                       float* __restrict__ out){
  int EP = (int)gmeta[NG];
  int sub = threadIdx.x & 7;
  int c8 = sub * 8;
  float w3r[8];
  #pragma unroll
  for (int t = 0; t < 8; ++t) w3r[t] = W3[c8 + t];
  float b3v = b3[0];
  int step = (gridDim.x * blockDim.x) >> 3;
  for (int i = (blockIdx.x * blockDim.x + threadIdx.x) >> 3; i < EP; i += step){
    int orig = __builtin_nontemporal_load(&eorig[i]);
    int gz = tilegid[i >> 5];
    U8 yv; yv.e = __builtin_nontemporal_load((const u32x4*)(y2b + (size_t)i * 64 + c8));
    const float* mg = mean2 + gz * 64 + c8;
    const float* rg = rstd2 + gz * 64 + c8;
    float4 m0 = *(const float4*)mg, m1 = *(const float4*)(mg + 4);
    float4 r0 = *(const float4*)rg, r1 = *(const float4*)(rg + 4);
    float a = 0.f;
    a += fmaxf(0.f, (b2f(yv.u[0]) - m0.x) * r0.x) * w3r[0];
    a += fmaxf(0.f, (b2f(yv.u[1]) - m0.y) * r0.y) * w3r[1];
    a += fmaxf(0.f, (b2f(yv.u[2]) - m0.z) * r0.z) * w3r[2];
    a += fmaxf(0.f, (b2f(yv.u[3]) - m0.w) * r0.w) * w3r[3];
    a += fmaxf(0.f, (b2f(yv.u[4]) - m1.x) * r1.x) * w3r[4];
    a += fmaxf(0.f, (b2f(yv.u[5]) - m1.y) * r1.y) * w3r[5];
    a += fmaxf(0.f, (b2f(yv.u[6]) - m1.z) * r1.z) * w3r[6];
    a += fmaxf(0.f, (b2f(yv.u[7]) - m1.w) * r1.w) * w3r[7];
    a += __shfl_xor(a, 1);
    a += __shfl_xor(a, 2);
    a += __shfl_xor(a, 4);
    if (sub == 0 && orig >= 0) out[orig] = a + b3v;
  }
}

extern "C" void kernel_launch(void* const* d_in, const int* in_sizes, int n_in,
                              void* d_out, int out_size, void* d_ws, size_t ws_size,
                              hipStream_t stream){
  const float* emb  = (const float*)d_in[0];
  const int*   ei   = (const int*)d_in[1];
  const int*   batch= (const int*)d_in[2];
  const float* W1   = (const float*)d_in[3];
  const float* b1   = (const float*)d_in[4];
  const float* W2   = (const float*)d_in[5];
  const float* b2   = (const float*)d_in[6];
  const float* W3   = (const float*)d_in[7];
  const float* b3   = (const float*)d_in[8];
  int N = in_sizes[0] / 64;
  int E = in_sizes[1] / 2;
  int EPMAX = E + NG * 32;   // upper bound on padded edge count
  float* out = (float*)d_out;

  char* w = (char*)d_ws;
  size_t off = 0;
  auto nxt = [&](size_t bytes) -> char* {
    char* p = w + off;
    off = (off + bytes + 255) & ~(size_t)255;
    return p;
  };
  unsigned short* WcF  = (unsigned short*)nxt(32 * 2 * 64 * 8 * 2);
  unsigned short* W2F  = (unsigned short*)nxt(4 * 8 * 64 * 8 * 2);
  unsigned short* PQb  = (unsigned short*)nxt((size_t)N * 512 * 2);
  unsigned short* y2b  = (unsigned short*)nxt((size_t)EPMAX * 64 * 2);
  int* ecn   = (int*)nxt((size_t)EPMAX * 4);
  int* ern   = (int*)nxt((size_t)EPMAX * 4);
  int* eorig = (int*)nxt((size_t)EPMAX * 4);
  int* tilegid = (int*)nxt((size_t)(EPMAX / 32 + 1) * 4);
  float* mean1 = (float*)nxt(NG * 256 * 4);
  float* rstd1 = (float*)nxt(NG * 256 * 4);
  float* mean2 = (float*)nxt(NG * 64 * 4);
  float* rstd2 = (float*)nxt(NG * 64 * 4);
  unsigned int* ncursor = (unsigned int*)nxt((size_t)N * 4);
  unsigned int* gmeta   = (unsigned int*)nxt((NG + 1) * 4);
  // zero-init region (contiguous, one memset)
  char* zbase = w + off;
  unsigned int* hist  = (unsigned int*)nxt(NG * 4);
  unsigned int* nodeh = (unsigned int*)nxt((size_t)N * 4);
  float* sum1 = (float*)nxt(NG * 256 * 4);
  float* sq1  = (float*)nxt(NG * 256 * 4);
  float* sum2 = (float*)nxt(NG * 64 * 4);
  float* sq2  = (float*)nxt(NG * 64 * 4);
  size_t zbytes = (size_t)((w + off) - zbase);
  hipMemsetAsync(zbase, 0, zbytes, stream);

  kprep<<<1024, 256, 0, stream>>>(W1, W2, ei, WcF, W2F, nodeh, E);
  khist<<<64, 256, 0, stream>>>(nodeh, batch, hist, N);
  kscan<<<NG, 256, 0, stream>>>(nodeh, hist, batch, ncursor, gmeta,
                                ecn, ern, eorig, tilegid, N);
  kscatter<<<2048, 256, 0, stream>>>(ei, E, ncursor, ern, eorig);
  {
    int tmmax = (N + 15) / 16;
    kgemm1<<<(tmmax + 3) / 4, 256, 0, stream>>>(emb, WcF, b1, PQb, N);
  }
  kstats1<<<(N + 31) / 32, 256, 0, stream>>>(PQb, ern, batch, ncursor, nodeh, sum1, sq1, N);
  kfin<<<(NG * 256 + 255) / 256, 256, 0, stream>>>(sum1, sq1, hist, mean1, rstd1, 256);
  knorm1<<<(N * 32 + 255) / 256, 256, 0, stream>>>(PQb, batch, mean1, rstd1, N);
  kmain<<<2048, 256, 0, stream>>>(PQb, W2F, ecn, ern, tilegid, rstd1, b2, hist, gmeta,
                                  y2b, sum2, sq2);
  kfin<<<(NG * 64 + 255) / 256, 256, 0, stream>>>(sum2, sq2, hist, mean2, rstd2, 64);
  kfinal<<<2048, 256, 0, stream>>>(y2b, eorig, tilegid, gmeta, mean2, rstd2, W3, b3, out);
}